// Round 2
// baseline (121.541 us; speedup 1.0000x reference)
//
#include <hip/hip_runtime.h>

#define N 4096
#define K 8
#define TB 128          // square tile dim (pair kernel), triangular tiling
#define NT (N / TB)     // 32 tiles per dim; 528 working blocks (ti<=tj)
#define RCH 16          // rows per staged chunk
#define NCH (TB / RCH)  // 8 chunks
#define TP 129          // Tbuf pitch in floats: 2-way bank alias only (free, m136)
#define NPB 16          // prep blocks (N/256)

__device__ __forceinline__ float fast_exp2(float x) { return __builtin_amdgcn_exp2f(x); }
__device__ __forceinline__ float fast_log2(float x) { return __builtin_amdgcn_logf(x); }
__device__ __forceinline__ float fast_sqrt(float x) { return __builtin_amdgcn_sqrtf(x); }

// Async global->LDS, 16B/lane; LDS dest = wave-uniform base + lane*16 (m97/m104).
// One call = 1 KB = two 128-float tile rows.
__device__ __forceinline__ void load_lds_16B(const float* g, float* l) {
    __builtin_amdgcn_global_load_lds((const __attribute__((address_space(1))) void*)g,
                                     (__attribute__((address_space(3))) void*)l,
                                     16, 0, 0);
}

// ---------------------------------------------------------------------------
// Pass 1: ZsT[n][k] = softmax_k(Z[:,n]); per-block partial
// Upart[blk][a*8+b] = sum_{n in blk} ZsT[n][a]*exp(C[n][b]).
// Diagonal correction is GONE: the triangular pair kernel never computes i==j.
// `out` is zeroed by hipMemsetAsync in kernel_launch.
// ---------------------------------------------------------------------------
__global__ __launch_bounds__(256) void prep_stats(
    const float* __restrict__ Z, const float* __restrict__ C,
    float* __restrict__ ZsT, float* __restrict__ Upart)
{
    const int t = threadIdx.x;
    const int n = blockIdx.x * 256 + t;
    const float L2E = 1.44269504f;

    __shared__ float zsL[256 * K];
    __shared__ float eL[256 * K];
    __shared__ float red[4][64];

    float z[K];
#pragma unroll
    for (int k = 0; k < K; ++k) z[k] = Z[k * N + n];   // coalesced column reads
    float zmax = z[0];
#pragma unroll
    for (int k = 1; k < K; ++k) zmax = fmaxf(zmax, z[k]);
    float zs[K];
    float zsum = 0.f;
#pragma unroll
    for (int k = 0; k < K; ++k) { zs[k] = fast_exp2((z[k] - zmax) * L2E); zsum += zs[k]; }
    const float inv = 1.f / zsum;
#pragma unroll
    for (int k = 0; k < K; ++k) zs[k] *= inv;

    float4* zst_p = (float4*)(ZsT + (size_t)n * K);
    zst_p[0] = make_float4(zs[0], zs[1], zs[2], zs[3]);
    zst_p[1] = make_float4(zs[4], zs[5], zs[6], zs[7]);

    const float4* c_p = (const float4*)(C + (size_t)n * K);
    const float4 c0 = c_p[0], c1 = c_p[1];
    float e[K];
    e[0] = fast_exp2(c0.x * L2E); e[1] = fast_exp2(c0.y * L2E);
    e[2] = fast_exp2(c0.z * L2E); e[3] = fast_exp2(c0.w * L2E);
    e[4] = fast_exp2(c1.x * L2E); e[5] = fast_exp2(c1.y * L2E);
    e[6] = fast_exp2(c1.z * L2E); e[7] = fast_exp2(c1.w * L2E);

#pragma unroll
    for (int k = 0; k < K; ++k) { zsL[t * K + k] = zs[k]; eL[t * K + k] = e[k]; }
    __syncthreads();

    const int cell = t & 63, q = t >> 6;
    const int a = cell >> 3, b = cell & 7;
    float s = 0.f;
    const int n0 = q * 64;
#pragma unroll 4
    for (int nn = 0; nn < 64; ++nn)
        s = fmaf(zsL[(n0 + nn) * K + a], eL[(n0 + nn) * K + b], s);
    red[q][cell] = s;
    __syncthreads();
    if (t < 64)
        Upart[blockIdx.x * 64 + t] = red[0][t] + red[1][t] + red[2][t] + red[3][t];
}

// ---------------------------------------------------------------------------
// Pass 2 (triangular): for unordered pairs i<j,
//   LL += theta_ij*(A_ij + A_ji) - 2*softplus(theta_ij)
// theta_ij uses the (i<j) orientation: dist^2 = |Mi'|^2 + |Mj|^2 - 2 Mi'.Mj,
// Mi' = M[i]+1e-6 — per-element fma sequence identical to the previous kernel.
// Halves the sqrt/exp2/log2/dist work vs the full-matrix version.
// Grid NT x NT; blocks with ti>tj exit. 528 working blocks (~2/CU).
// A_ij slab staged via global_load_lds (linear dest); mirror slab A[j][i]
// reg-staged then ds_written transposed into pitch-TP LDS (2-way alias, free).
// Both double-buffered: chunk c+1 loads fly under chunk c compute.
// ---------------------------------------------------------------------------
__global__ __launch_bounds__(256) void pair_ll(
    const float* __restrict__ A, const float* __restrict__ beta,
    const float* __restrict__ a_ptr, const float* __restrict__ ZsT,
    const float* __restrict__ Upart, float* __restrict__ out)
{
    const int ti = blockIdx.x, tj = blockIdx.y;
    if (ti > tj) return;                  // lower-triangle blocks: no work
    const bool dTile = (ti == tj);

    const int t = threadIdx.x;
    const int lane = t & 63, w = t >> 6;
    const int i0 = ti * TB, jb = tj * TB;
    const int jl = t & 127, h = t >> 7;   // column-in-tile, row-half
    const int j = jb + jl;
    const float L2E = 1.44269504f;
    const float LN2 = 0.69314718f;

    __shared__ __align__(16) float Abuf[2][RCH][TB];   // 16 KB  A[i][j] slab
    __shared__ float Tbuf[2][RCH][TP];                 // 16.5KB A[j][i] slab (transposed)
    __shared__ __align__(16) float4 ntwoMi[TB][2];     // -2*(M[i]+1e-6)
    __shared__ __align__(8)  float2 rc[TB];            // {|Mi'|^2, beta_i*L2E}
    __shared__ float UL[64];
    __shared__ float wsum[4];

// Abuf staging: 16 rows x 512B; one wave-call covers 2 rows. Wave w: rows w*4..w*4+3.
#define STAGE_ABUF(B, CH)                                                          \
    {                                                                              \
        const float* g_ = A + (size_t)(i0 + (CH) * RCH + w * 4 + (lane >> 5)) * N  \
                          + jb + (lane & 31) * 4;                                  \
        load_lds_16B(g_,         &Abuf[B][w * 4][0]);                              \
        load_lds_16B(g_ + 2 * N, &Abuf[B][w * 4 + 2][0]);                          \
    }

// Mirror slab: thread t loads 8 floats of row jb+(t>>1), cols i0+CH*16+(t&1)*8.
// Lane pairs (2m,2m+1) cover 64B contiguous of one row; next chunk uses the
// other half of each 128B line (L2-resident between chunks).
#define STAGE_TREG(CH)                                                             \
    {                                                                              \
        const float* g_ = A + (size_t)(jb + (t >> 1)) * N + i0 + (CH) * RCH        \
                          + (t & 1) * 8;                                           \
        tr0 = *(const float4*)(g_);                                                \
        tr1 = *(const float4*)(g_ + 4);                                            \
    }

// Transposed write: Tbuf[r][m], r=(t&1)*8+k, m=t>>1. Pitch TP=129 -> writes and
// reads are 2-way bank aliases only (free per m136).
#define TBUF_WRITE(B)                                                              \
    {                                                                              \
        const int rb_ = (t & 1) * 8, m_ = t >> 1;                                  \
        Tbuf[B][rb_ + 0][m_] = tr0.x; Tbuf[B][rb_ + 1][m_] = tr0.y;                \
        Tbuf[B][rb_ + 2][m_] = tr0.z; Tbuf[B][rb_ + 3][m_] = tr0.w;                \
        Tbuf[B][rb_ + 4][m_] = tr1.x; Tbuf[B][rb_ + 5][m_] = tr1.y;                \
        Tbuf[B][rb_ + 6][m_] = tr1.z; Tbuf[B][rb_ + 7][m_] = tr1.w;                \
    }

// Per-chunk compute: each thread does its 8 rows (h*8..h*8+7) for column jl.
// DIAGM: mask out i>=j on diagonal tiles (uniform branch selects variant).
#define CHUNK_COMPUTE(DIAGM)                                                       \
    _Pragma("unroll")                                                              \
    for (int k = 0; k < 8; ++k) {                                                  \
        const int rl = h * 8 + k;                                                  \
        const int il = c * RCH + rl;                                               \
        const float av = Abuf[buf][rl][jl];                                        \
        const float tv = Tbuf[buf][rl][jl];                                        \
        const float4 tm0 = ntwoMi[il][0];                                          \
        const float4 tm1 = ntwoMi[il][1];                                          \
        const float2 cc = rc[il];                                                  \
        float ss = cc.x + mjn2;                                                    \
        ss = fmaf(tm0.x, mj[0], ss); ss = fmaf(tm0.y, mj[1], ss);                  \
        ss = fmaf(tm0.z, mj[2], ss); ss = fmaf(tm0.w, mj[3], ss);                  \
        ss = fmaf(tm1.x, mj[4], ss); ss = fmaf(tm1.y, mj[5], ss);                  \
        ss = fmaf(tm1.z, mj[6], ss); ss = fmaf(tm1.w, mj[7], ss);                  \
        ss = fmaxf(ss, 0.f);                                                       \
        const float dist = fast_sqrt(ss);                                          \
        const float t2 = fmaf(naL2E, dist, cc.y + bjL2E);                          \
        const float ex = fast_exp2(t2);                                            \
        const float lp = fast_log2(1.f + ex);                                      \
        const float wgt = av + tv;                                                 \
        if (DIAGM) {                                                               \
            const float msk = (il < jl) ? 1.f : 0.f;                               \
            acc_t = fmaf(t2, wgt * msk, acc_t);                                    \
            acc_l = fmaf(msk, lp, acc_l);                                          \
        } else {                                                                   \
            acc_t = fmaf(t2, wgt, acc_t);                                          \
            acc_l += lp;                                                           \
        }                                                                          \
    }

    float4 tr0, tr1;

    // issue chunk-0 staging FIRST: overlaps the whole constants prologue
    STAGE_ABUF(0, 0);
    STAGE_TREG(0);

    // fold Upart -> U (same order as before)
    if (t < 64) {
        float s = 0.f;
#pragma unroll
        for (int blk = 0; blk < NPB; ++blk) s += Upart[blk * 64 + t];
        UL[t] = s;
    }
    __syncthreads();

    // per-thread Sinv (deterministic, same arithmetic as before)
    float sinv[8];
#pragma unroll
    for (int b = 0; b < 8; ++b) {
        float s = 0.f;
#pragma unroll
        for (int a = 0; a < 8; ++a) s += UL[a * 8 + b];
        sinv[b] = 1.f / s;
    }

    // column-side M for this thread's j
    const float4* zp = (const float4*)(ZsT + (size_t)j * K);
    const float4 z0 = zp[0], z1 = zp[1];
    float wv[K] = { z0.x * sinv[0], z0.y * sinv[1], z0.z * sinv[2], z0.w * sinv[3],
                    z1.x * sinv[4], z1.y * sinv[5], z1.z * sinv[6], z1.w * sinv[7] };
    float mj[K];
#pragma unroll
    for (int k = 0; k < K; ++k) {
        float acc = 0.f;
#pragma unroll
        for (int kk = 0; kk < K; ++kk) acc = fmaf(UL[k * K + kk], wv[kk], acc);
        mj[k] = acc;
    }
    float mjn2 = mj[0] * mj[0];
#pragma unroll
    for (int k = 1; k < K; ++k) mjn2 = fmaf(mj[k], mj[k], mjn2);
    const float bjL2E = beta[j] * L2E;
    const float naL2E = -a_ptr[0] * L2E;

    // row-side constants for the 128-row panel
    if (t < TB) {
        const float4* zp2 = (const float4*)(ZsT + (size_t)(i0 + t) * K);
        const float4 y0 = zp2[0], y1 = zp2[1];
        float wr[K] = { y0.x * sinv[0], y0.y * sinv[1], y0.z * sinv[2], y0.w * sinv[3],
                        y1.x * sinv[4], y1.y * sinv[5], y1.z * sinv[6], y1.w * sinv[7] };
        float v[K];
#pragma unroll
        for (int k = 0; k < K; ++k) {
            float acc = 0.f;
#pragma unroll
            for (int kk = 0; kk < K; ++kk) acc = fmaf(UL[k * K + kk], wr[kk], acc);
            v[k] = acc + 1e-6f;
        }
        float s2 = 0.f;
#pragma unroll
        for (int k = 0; k < K; ++k) s2 = fmaf(v[k], v[k], s2);
        ntwoMi[t][0] = make_float4(-2.f * v[0], -2.f * v[1], -2.f * v[2], -2.f * v[3]);
        ntwoMi[t][1] = make_float4(-2.f * v[4], -2.f * v[5], -2.f * v[6], -2.f * v[7]);
        rc[t] = make_float2(s2, beta[i0 + t] * L2E);
    }

    TBUF_WRITE(0);       // vmcnt wait on tr0/tr1 overlapped with the work above
    __syncthreads();     // Tbuf[0] visible; Abuf chunk-0 drained (vmcnt(0))

    float acc_t = 0.f, acc_l = 0.f;
    int buf = 0;
    for (int c = 0; c < NCH; ++c) {
        if (c + 1 < NCH) { STAGE_ABUF(buf ^ 1, c + 1); STAGE_TREG(c + 1); }
        if (dTile) { CHUNK_COMPUTE(true) } else { CHUNK_COMPUTE(false) }
        if (c + 1 < NCH) {
            TBUF_WRITE(buf ^ 1);   // waits on this iter's Treg loads (post-compute)
            __syncthreads();       // drains Abuf c+1 loads; publishes Tbuf c+1
        }
        buf ^= 1;
    }
    // pair contribution: theta*(Aij+Aji) - 2*softplus  =>  LN2*(acc_t - 2*acc_l)
    float acc = LN2 * (acc_t - 2.f * acc_l);

    for (int off = 32; off > 0; off >>= 1) acc += __shfl_down(acc, off, 64);
    if (lane == 0) wsum[w] = acc;
    __syncthreads();
    if (t == 0) atomicAdd(out, wsum[0] + wsum[1] + wsum[2] + wsum[3]);
}

extern "C" void kernel_launch(void* const* d_in, const int* in_sizes, int n_in,
                              void* d_out, int out_size, void* d_ws, size_t ws_size,
                              hipStream_t stream)
{
    const float* A    = (const float*)d_in[0];   // [N,N]
    const float* beta = (const float*)d_in[1];   // [N]
    const float* a    = (const float*)d_in[2];   // [1]
    const float* Z    = (const float*)d_in[3];   // [K,N]
    const float* C    = (const float*)d_in[4];   // [N,K]
    float* out = (float*)d_out;

    float* ws    = (float*)d_ws;
    float* ZsT   = ws;                      // N*K floats
    float* Upart = ws + (size_t)N * K;      // NPB*64 floats

    hipMemsetAsync(out, 0, sizeof(float), stream);   // harness poisons out each call

    prep_stats<<<NPB, 256, 0, stream>>>(Z, C, ZsT, Upart);

    dim3 grid(NT, NT);                      // ti>tj blocks exit immediately
    pair_ll<<<grid, 256, 0, stream>>>(A, beta, a, ZsT, Upart, out);
}

// Round 3
// 112.789 us; speedup vs baseline: 1.0776x; 1.0776x over previous
//
#include <hip/hip_runtime.h>

#define N 4096
#define K 8
#define RB 64           // rows of A per block (pair kernel)
#define CB 256          // columns of A per block (one per thread)
#define RCH 8           // rows per chunk (was 16): halves LDS -> 5 blocks/CU
#define NCH (RB / RCH)  // chunks per block
#define NPB 16          // prep blocks (N/256)

__device__ __forceinline__ float fast_exp2(float x) { return __builtin_amdgcn_exp2f(x); }
__device__ __forceinline__ float fast_log2(float x) { return __builtin_amdgcn_logf(x); }
__device__ __forceinline__ float fast_sqrt(float x) { return __builtin_amdgcn_sqrtf(x); }

// Async global->LDS, 16B per lane. LDS dest is wave-uniform base; lane i
// lands at base + i*16 (m97/m104 semantics). One call = one 256-float row.
__device__ __forceinline__ void load_lds_16B(const float* g, float* l) {
    __builtin_amdgcn_global_load_lds((const __attribute__((address_space(1))) void*)g,
                                     (__attribute__((address_space(3))) void*)l,
                                     16, 0, 0);
}

// ---------------------------------------------------------------------------
// Pass 1: ZsT[n][k] = softmax_k(Z[:,n]); per-block partial
// Upart[blk][a*8+b] = sum_{n in blk} ZsT[n][a]*exp(C[n][b]).
// Diagonal correction (needs only diag(A), beta, a) fused at the end.
// `out` is zeroed by hipMemsetAsync in kernel_launch.
// ---------------------------------------------------------------------------
__global__ __launch_bounds__(256) void prep_stats(
    const float* __restrict__ Z, const float* __restrict__ C,
    const float* __restrict__ A, const float* __restrict__ beta,
    const float* __restrict__ a_ptr,
    float* __restrict__ ZsT, float* __restrict__ Upart, float* __restrict__ out)
{
    const int t = threadIdx.x;
    const int n = blockIdx.x * 256 + t;
    const float L2E = 1.44269504f;
    const float LN2 = 0.69314718f;

    __shared__ float zsL[256 * K];
    __shared__ float eL[256 * K];
    __shared__ float red[4][64];
    __shared__ float dsum[4];

    // issue the scattered diag load early; consumed at the very end
    const float av_diag = A[(size_t)n * N + n];
    const float bn = beta[n];
    const float a_v = a_ptr[0];

    float z[K];
#pragma unroll
    for (int k = 0; k < K; ++k) z[k] = Z[k * N + n];   // coalesced column reads
    float zmax = z[0];
#pragma unroll
    for (int k = 1; k < K; ++k) zmax = fmaxf(zmax, z[k]);
    float zs[K];
    float zsum = 0.f;
#pragma unroll
    for (int k = 0; k < K; ++k) { zs[k] = fast_exp2((z[k] - zmax) * L2E); zsum += zs[k]; }
    const float inv = 1.f / zsum;
#pragma unroll
    for (int k = 0; k < K; ++k) zs[k] *= inv;

    float4* zst_p = (float4*)(ZsT + (size_t)n * K);
    zst_p[0] = make_float4(zs[0], zs[1], zs[2], zs[3]);
    zst_p[1] = make_float4(zs[4], zs[5], zs[6], zs[7]);

    const float4* c_p = (const float4*)(C + (size_t)n * K);
    const float4 c0 = c_p[0], c1 = c_p[1];
    float e[K];
    e[0] = fast_exp2(c0.x * L2E); e[1] = fast_exp2(c0.y * L2E);
    e[2] = fast_exp2(c0.z * L2E); e[3] = fast_exp2(c0.w * L2E);
    e[4] = fast_exp2(c1.x * L2E); e[5] = fast_exp2(c1.y * L2E);
    e[6] = fast_exp2(c1.z * L2E); e[7] = fast_exp2(c1.w * L2E);

#pragma unroll
    for (int k = 0; k < K; ++k) { zsL[t * K + k] = zs[k]; eL[t * K + k] = e[k]; }
    __syncthreads();

    const int cell = t & 63, q = t >> 6;
    const int a = cell >> 3, b = cell & 7;
    float s = 0.f;
    const int n0 = q * 64;
#pragma unroll 4
    for (int nn = 0; nn < 64; ++nn)
        s = fmaf(zsL[(n0 + nn) * K + a], eL[(n0 + nn) * K + b], s);
    red[q][cell] = s;
    __syncthreads();
    if (t < 64)
        Upart[blockIdx.x * 64 + t] = red[0][t] + red[1][t] + red[2][t] + red[3][t];

    // ---- diagonal correction ----
    const float theta = fmaf(-a_v, 2.8284271247e-6f, 2.f * bn);
    const float ex = fast_exp2(theta * L2E);
    const float sp = LN2 * fast_log2(1.f + ex);
    float d = fmaf(theta, av_diag, -sp);
    for (int off = 32; off > 0; off >>= 1) d += __shfl_down(d, off, 64);
    const int lane = t & 63, wd = t >> 6;
    if (lane == 0) dsum[wd] = d;
    __syncthreads();
    if (t == 0) atomicAdd(out, -(dsum[0] + dsum[1] + dsum[2] + dsum[3]));
}

// ---------------------------------------------------------------------------
// Pass 2: LL += sum_{all i,j} theta_ij*A_ij - softplus(theta_ij)
// theta = beta_i + beta_j - a*sqrt(|Mi'|^2 + |Mj|^2 - 2 Mi'.Mj), Mi' = M[i]+1e-6.
// M derived in-block from ZsT/Upart (identical fma order to the old prep_M).
// A staged via async global_load_lds (16B/lane; 1 call = one 256-float row),
// double-buffered: chunk c+1 loads fly while chunk c computes.
// RCH=8: LDS ~18.8 KB -> 5 blocks/CU (VGPR-capped), up from 4 at RCH=16.
// ---------------------------------------------------------------------------
__global__ __launch_bounds__(256) void pair_ll(
    const float* __restrict__ A, const float* __restrict__ beta,
    const float* __restrict__ a_ptr, const float* __restrict__ ZsT,
    const float* __restrict__ Upart, float* __restrict__ out)
{
    const int t = threadIdx.x;
    const int lane = t & 63, w = t >> 6;
    const int i0 = blockIdx.x * RB;
    const int jbase = blockIdx.y * CB;
    const int j = jbase + t;
    const float L2E = 1.44269504f;
    const float LN2 = 0.69314718f;

    __shared__ __align__(16) float Abuf[2][RCH][CB];   // 16 KB
    __shared__ __align__(16) float4 ntwoMi[RB][2];     // -2*(M[i]+1e-6)
    __shared__ __align__(8)  float2 rc[RB];            // {|Mi'|^2, beta_i*L2E}
    __shared__ float UL[64];
    __shared__ float wsum[4];

    // issue chunk-0 staging FIRST: overlaps the whole M-derivation prologue.
    // wave w stages rows w*2, w*2+1 of the 8-row chunk (one call = one row).
    {
        const float* g = A + (size_t)(i0 + w * 2) * N + jbase + lane * 4;
        load_lds_16B(g,     &Abuf[0][w * 2][0]);
        load_lds_16B(g + N, &Abuf[0][w * 2 + 1][0]);
    }

    // fold Upart -> U (same blk 0..15 order as always)
    if (t < 64) {
        float s = 0.f;
#pragma unroll
        for (int blk = 0; blk < NPB; ++blk) s += Upart[blk * 64 + t];
        UL[t] = s;
    }
    __syncthreads();

    // per-thread Sinv (deterministic, same arithmetic as before)
    float sinv[8];
#pragma unroll
    for (int b = 0; b < 8; ++b) {
        float s = 0.f;
#pragma unroll
        for (int a = 0; a < 8; ++a) s += UL[a * 8 + b];
        sinv[b] = 1.f / s;
    }

    // column-side M for this thread's j
    const float4* zp = (const float4*)(ZsT + (size_t)j * K);
    const float4 z0 = zp[0], z1 = zp[1];
    float wv[K] = { z0.x * sinv[0], z0.y * sinv[1], z0.z * sinv[2], z0.w * sinv[3],
                    z1.x * sinv[4], z1.y * sinv[5], z1.z * sinv[6], z1.w * sinv[7] };
    float mj[K];
#pragma unroll
    for (int k = 0; k < K; ++k) {
        float acc = 0.f;
#pragma unroll
        for (int kk = 0; kk < K; ++kk) acc = fmaf(UL[k * K + kk], wv[kk], acc);
        mj[k] = acc;
    }
    float mj2 = mj[0] * mj[0];
#pragma unroll
    for (int k = 1; k < K; ++k) mj2 = fmaf(mj[k], mj[k], mj2);
    const float bjL2E = beta[j] * L2E;
    const float naL2E = -a_ptr[0] * L2E;

    // row-side constants for the 64-row panel
    if (t < RB) {
        const float4* zp2 = (const float4*)(ZsT + (size_t)(i0 + t) * K);
        const float4 y0 = zp2[0], y1 = zp2[1];
        float wr[K] = { y0.x * sinv[0], y0.y * sinv[1], y0.z * sinv[2], y0.w * sinv[3],
                        y1.x * sinv[4], y1.y * sinv[5], y1.z * sinv[6], y1.w * sinv[7] };
        float v[K];
#pragma unroll
        for (int k = 0; k < K; ++k) {
            float acc = 0.f;
#pragma unroll
            for (int kk = 0; kk < K; ++kk) acc = fmaf(UL[k * K + kk], wr[kk], acc);
            v[k] = acc + 1e-6f;
        }
        float s2 = 0.f;
#pragma unroll
        for (int k = 0; k < K; ++k) s2 = fmaf(v[k], v[k], s2);
        ntwoMi[t][0] = make_float4(-2.f * v[0], -2.f * v[1], -2.f * v[2], -2.f * v[3]);
        ntwoMi[t][1] = make_float4(-2.f * v[4], -2.f * v[5], -2.f * v[6], -2.f * v[7]);
        rc[t] = make_float2(s2, beta[i0 + t] * L2E);
    }
    __syncthreads();   // row constants visible; chunk-0 staging drained (vmcnt(0))

    float acc_t = 0.f, acc_l = 0.f;
    int buf = 0;
    for (int c = 0; c < NCH; ++c) {
        if (c + 1 < NCH) {   // issue next chunk; flies during this chunk's compute
            const float* g = A + (size_t)(i0 + (c + 1) * RCH + w * 2) * N + jbase + lane * 4;
            load_lds_16B(g,     &Abuf[buf ^ 1][w * 2][0]);
            load_lds_16B(g + N, &Abuf[buf ^ 1][w * 2 + 1][0]);
        }
#pragma unroll
        for (int r = 0; r < RCH; ++r) {
            const int ir = c * RCH + r;
            const float av = Abuf[buf][r][t];       // stride-1 LDS, conflict-free
            const float4 tm0 = ntwoMi[ir][0];       // b128 broadcast
            const float4 tm1 = ntwoMi[ir][1];
            const float2 cc = rc[ir];
            float ss = cc.x + mj2;
            ss = fmaf(tm0.x, mj[0], ss); ss = fmaf(tm0.y, mj[1], ss);
            ss = fmaf(tm0.z, mj[2], ss); ss = fmaf(tm0.w, mj[3], ss);
            ss = fmaf(tm1.x, mj[4], ss); ss = fmaf(tm1.y, mj[5], ss);
            ss = fmaf(tm1.z, mj[6], ss); ss = fmaf(tm1.w, mj[7], ss);
            ss = fmaxf(ss, 0.f);                    // cancellation guard
            const float dist = fast_sqrt(ss);
            const float t2 = fmaf(naL2E, dist, cc.y + bjL2E);  // theta*log2(e)
            const float ex = fast_exp2(t2);                    // exp(theta), safe
            const float lp = fast_log2(1.f + ex);              // softplus/ln2
            acc_t = fmaf(t2, av, acc_t);
            acc_l += lp;
        }
        if (c + 1 < NCH) __syncthreads();  // drains next chunk's loads, guards dbuf swap
        buf ^= 1;
    }
    float acc = LN2 * (acc_t - acc_l);

    for (int off = 32; off > 0; off >>= 1) acc += __shfl_down(acc, off, 64);
    if (lane == 0) wsum[w] = acc;
    __syncthreads();
    if (t == 0) atomicAdd(out, wsum[0] + wsum[1] + wsum[2] + wsum[3]);
}

extern "C" void kernel_launch(void* const* d_in, const int* in_sizes, int n_in,
                              void* d_out, int out_size, void* d_ws, size_t ws_size,
                              hipStream_t stream)
{
    const float* A    = (const float*)d_in[0];   // [N,N]
    const float* beta = (const float*)d_in[1];   // [N]
    const float* a    = (const float*)d_in[2];   // [1]
    const float* Z    = (const float*)d_in[3];   // [K,N]
    const float* C    = (const float*)d_in[4];   // [N,K]
    float* out = (float*)d_out;

    float* ws    = (float*)d_ws;
    float* ZsT   = ws;                      // N*K floats
    float* Upart = ws + (size_t)N * K;      // NPB*64 floats

    hipMemsetAsync(out, 0, sizeof(float), stream);   // harness poisons out each call

    prep_stats<<<NPB, 256, 0, stream>>>(Z, C, A, beta, a, ZsT, Upart, out);

    dim3 grid(N / RB, N / CB);
    pair_ll<<<grid, 256, 0, stream>>>(A, beta, a, ZsT, Upart, out);
}

// Round 4
// 109.359 us; speedup vs baseline: 1.1114x; 1.0314x over previous
//
#include <hip/hip_runtime.h>

#define N 4096
#define K 8
#define RB 64           // rows of A per block (pair kernel)
#define CB 256          // columns of A per block (one per thread)
#define WCOLS 64        // columns per wave slab (wave-private staging)
#define RCH 8           // rows per chunk
#define NCH (RB / RCH)  // chunks per block
#define NPB 16          // prep blocks (N/256)

__device__ __forceinline__ float fast_exp2(float x) { return __builtin_amdgcn_exp2f(x); }
__device__ __forceinline__ float fast_log2(float x) { return __builtin_amdgcn_logf(x); }
__device__ __forceinline__ float fast_sqrt(float x) { return __builtin_amdgcn_sqrtf(x); }

// Async global->LDS, 16B per lane. LDS dest is wave-uniform base; lane i lands
// at base + i*16 (m97/m104). Global source address is per-lane.
__device__ __forceinline__ void load_lds_16B(const float* g, float* l) {
    __builtin_amdgcn_global_load_lds((const __attribute__((address_space(1))) void*)g,
                                     (__attribute__((address_space(3))) void*)l,
                                     16, 0, 0);
}

// ---------------------------------------------------------------------------
// Pass 1: ZsT[n][k] = softmax_k(Z[:,n]); per-block partial
// Upart[blk][a*8+b] = sum_{n in blk} ZsT[n][a]*exp(C[n][b]).
// Diagonal correction (needs only diag(A), beta, a) fused at the end.
// `out` is zeroed by hipMemsetAsync in kernel_launch.
// ---------------------------------------------------------------------------
__global__ __launch_bounds__(256) void prep_stats(
    const float* __restrict__ Z, const float* __restrict__ C,
    const float* __restrict__ A, const float* __restrict__ beta,
    const float* __restrict__ a_ptr,
    float* __restrict__ ZsT, float* __restrict__ Upart, float* __restrict__ out)
{
    const int t = threadIdx.x;
    const int n = blockIdx.x * 256 + t;
    const float L2E = 1.44269504f;
    const float LN2 = 0.69314718f;

    __shared__ float zsL[256 * K];
    __shared__ float eL[256 * K];
    __shared__ float red[4][64];
    __shared__ float dsum[4];

    // issue the scattered diag load early; consumed at the very end
    const float av_diag = A[(size_t)n * N + n];
    const float bn = beta[n];
    const float a_v = a_ptr[0];

    float z[K];
#pragma unroll
    for (int k = 0; k < K; ++k) z[k] = Z[k * N + n];   // coalesced column reads
    float zmax = z[0];
#pragma unroll
    for (int k = 1; k < K; ++k) zmax = fmaxf(zmax, z[k]);
    float zs[K];
    float zsum = 0.f;
#pragma unroll
    for (int k = 0; k < K; ++k) { zs[k] = fast_exp2((z[k] - zmax) * L2E); zsum += zs[k]; }
    const float inv = 1.f / zsum;
#pragma unroll
    for (int k = 0; k < K; ++k) zs[k] *= inv;

    float4* zst_p = (float4*)(ZsT + (size_t)n * K);
    zst_p[0] = make_float4(zs[0], zs[1], zs[2], zs[3]);
    zst_p[1] = make_float4(zs[4], zs[5], zs[6], zs[7]);

    const float4* c_p = (const float4*)(C + (size_t)n * K);
    const float4 c0 = c_p[0], c1 = c_p[1];
    float e[K];
    e[0] = fast_exp2(c0.x * L2E); e[1] = fast_exp2(c0.y * L2E);
    e[2] = fast_exp2(c0.z * L2E); e[3] = fast_exp2(c0.w * L2E);
    e[4] = fast_exp2(c1.x * L2E); e[5] = fast_exp2(c1.y * L2E);
    e[6] = fast_exp2(c1.z * L2E); e[7] = fast_exp2(c1.w * L2E);

#pragma unroll
    for (int k = 0; k < K; ++k) { zsL[t * K + k] = zs[k]; eL[t * K + k] = e[k]; }
    __syncthreads();

    const int cell = t & 63, q = t >> 6;
    const int a = cell >> 3, b = cell & 7;
    float s = 0.f;
    const int n0 = q * 64;
#pragma unroll 4
    for (int nn = 0; nn < 64; ++nn)
        s = fmaf(zsL[(n0 + nn) * K + a], eL[(n0 + nn) * K + b], s);
    red[q][cell] = s;
    __syncthreads();
    if (t < 64)
        Upart[blockIdx.x * 64 + t] = red[0][t] + red[1][t] + red[2][t] + red[3][t];

    // ---- diagonal correction ----
    const float theta = fmaf(-a_v, 2.8284271247e-6f, 2.f * bn);
    const float ex = fast_exp2(theta * L2E);
    const float sp = LN2 * fast_log2(1.f + ex);
    float d = fmaf(theta, av_diag, -sp);
    for (int off = 32; off > 0; off >>= 1) d += __shfl_down(d, off, 64);
    const int lane = t & 63, wd = t >> 6;
    if (lane == 0) dsum[wd] = d;
    __syncthreads();
    if (t == 0) atomicAdd(out, -(dsum[0] + dsum[1] + dsum[2] + dsum[3]));
}

// ---------------------------------------------------------------------------
// Pass 2: LL += sum_{all i,j} theta_ij*A_ij - softplus(theta_ij)
// theta = beta_i + beta_j - a*sqrt(|Mi'|^2 + |Mj|^2 - 2 Mi'.Mj), Mi' = M[i]+1e-6.
// WAVE-PRIVATE STAGING: wave w owns the 64-col slab [jbase+w*64, +64); it
// stages its own rows into its own double-buffered LDS region. Thread t still
// owns column jbase+t (t = w*64+lane), so per-element math and accumulation
// order are identical to the previous version. NO __syncthreads in the main
// loop: sync is a per-wave s_waitcnt vmcnt(0) placed right before the chunk's
// LDS reads (at that point the only outstanding VMEM = this chunk's 2 staging
// loads -> exact counted wait). av pulled to regs BEFORE issuing next chunk's
// stage, so the next loads fly under register-only math. Waves slip freely.
// ---------------------------------------------------------------------------
__global__ __launch_bounds__(256) void pair_ll(
    const float* __restrict__ A, const float* __restrict__ beta,
    const float* __restrict__ a_ptr, const float* __restrict__ ZsT,
    const float* __restrict__ Upart, float* __restrict__ out)
{
    const int t = threadIdx.x;
    const int lane = t & 63, w = t >> 6;
    const int i0 = blockIdx.x * RB;
    const int jbase = blockIdx.y * CB;
    const int j = jbase + t;              // == jbase + w*64 + lane
    const float L2E = 1.44269504f;
    const float LN2 = 0.69314718f;

    __shared__ __align__(16) float Abuf[4][2][RCH][WCOLS];  // 16 KB, wave-private
    __shared__ __align__(16) float4 ntwoMi[RB][2];          // -2*(M[i]+1e-6)
    __shared__ __align__(8)  float2 rc[RB];                 // {|Mi'|^2, beta_i*L2E}
    __shared__ float UL[64];
    __shared__ float wsum[4];

    // per-lane source addressing for the wave's slab:
    // lane l stages row (l>>4) of the call, cols (l&15)*4 .. +3 of the slab.
    const int lr = lane >> 4;
    const int lc = (lane & 15) << 2;
    const float* gbase = A + (size_t)(i0 + lr) * N + jbase + w * WCOLS + lc;

    // one STAGE = 8 rows x 64 cols = 2 KB = 2 calls (4 rows each)
#define STAGE(B, CH)                                                           \
    {                                                                          \
        const float* g_ = gbase + (size_t)(CH) * RCH * N;                      \
        load_lds_16B(g_,         &Abuf[w][B][0][0]);                           \
        load_lds_16B(g_ + 4 * N, &Abuf[w][B][4][0]);                           \
    }

    // issue chunk 0 FIRST: overlaps the whole M-derivation prologue
    STAGE(0, 0);

    // fold Upart -> U (same blk 0..15 order as always)
    if (t < 64) {
        float s = 0.f;
#pragma unroll
        for (int blk = 0; blk < NPB; ++blk) s += Upart[blk * 64 + t];
        UL[t] = s;
    }
    __syncthreads();

    // per-thread Sinv (deterministic, same arithmetic as before)
    float sinv[8];
#pragma unroll
    for (int b = 0; b < 8; ++b) {
        float s = 0.f;
#pragma unroll
        for (int a = 0; a < 8; ++a) s += UL[a * 8 + b];
        sinv[b] = 1.f / s;
    }

    // column-side M for this thread's j
    const float4* zp = (const float4*)(ZsT + (size_t)j * K);
    const float4 z0 = zp[0], z1 = zp[1];
    float wv[K] = { z0.x * sinv[0], z0.y * sinv[1], z0.z * sinv[2], z0.w * sinv[3],
                    z1.x * sinv[4], z1.y * sinv[5], z1.z * sinv[6], z1.w * sinv[7] };
    float mj[K];
#pragma unroll
    for (int k = 0; k < K; ++k) {
        float acc = 0.f;
#pragma unroll
        for (int kk = 0; kk < K; ++kk) acc = fmaf(UL[k * K + kk], wv[kk], acc);
        mj[k] = acc;
    }
    float mj2 = mj[0] * mj[0];
#pragma unroll
    for (int k = 1; k < K; ++k) mj2 = fmaf(mj[k], mj[k], mj2);
    const float bjL2E = beta[j] * L2E;
    const float naL2E = -a_ptr[0] * L2E;

    // row-side constants for the 64-row panel
    if (t < RB) {
        const float4* zp2 = (const float4*)(ZsT + (size_t)(i0 + t) * K);
        const float4 y0 = zp2[0], y1 = zp2[1];
        float wr[K] = { y0.x * sinv[0], y0.y * sinv[1], y0.z * sinv[2], y0.w * sinv[3],
                        y1.x * sinv[4], y1.y * sinv[5], y1.z * sinv[6], y1.w * sinv[7] };
        float v[K];
#pragma unroll
        for (int k = 0; k < K; ++k) {
            float acc = 0.f;
#pragma unroll
            for (int kk = 0; kk < K; ++kk) acc = fmaf(UL[k * K + kk], wr[kk], acc);
            v[k] = acc + 1e-6f;
        }
        float s2 = 0.f;
#pragma unroll
        for (int k = 0; k < K; ++k) s2 = fmaf(v[k], v[k], s2);
        ntwoMi[t][0] = make_float4(-2.f * v[0], -2.f * v[1], -2.f * v[2], -2.f * v[3]);
        ntwoMi[t][1] = make_float4(-2.f * v[4], -2.f * v[5], -2.f * v[6], -2.f * v[7]);
        rc[t] = make_float2(s2, beta[i0 + t] * L2E);
    }
    __syncthreads();   // publishes UL/ntwoMi/rc; also drains chunk-0 staging

    float acc_t = 0.f, acc_l = 0.f;
    int buf = 0;
    for (int c = 0; c < NCH; ++c) {
        // chunk c ready: only its own 2 staging loads can be outstanding here
        asm volatile("s_waitcnt vmcnt(0)" ::: "memory");
        float av[RCH];
#pragma unroll
        for (int r = 0; r < RCH; ++r) av[r] = Abuf[w][buf][r][lane];
        if (c + 1 < NCH) STAGE(buf ^ 1, c + 1);   // flies under the math below
#pragma unroll
        for (int r = 0; r < RCH; ++r) {
            const int ir = c * RCH + r;
            const float4 tm0 = ntwoMi[ir][0];       // b128 broadcast
            const float4 tm1 = ntwoMi[ir][1];
            const float2 cc = rc[ir];
            float ss = cc.x + mj2;
            ss = fmaf(tm0.x, mj[0], ss); ss = fmaf(tm0.y, mj[1], ss);
            ss = fmaf(tm0.z, mj[2], ss); ss = fmaf(tm0.w, mj[3], ss);
            ss = fmaf(tm1.x, mj[4], ss); ss = fmaf(tm1.y, mj[5], ss);
            ss = fmaf(tm1.z, mj[6], ss); ss = fmaf(tm1.w, mj[7], ss);
            ss = fmaxf(ss, 0.f);                    // cancellation guard
            const float dist = fast_sqrt(ss);
            const float t2 = fmaf(naL2E, dist, cc.y + bjL2E);  // theta*log2(e)
            const float ex = fast_exp2(t2);                    // exp(theta), safe
            const float lp = fast_log2(1.f + ex);              // softplus/ln2
            acc_t = fmaf(t2, av[r], acc_t);
            acc_l += lp;
        }
        buf ^= 1;
    }
    float acc = LN2 * (acc_t - acc_l);

    for (int off = 32; off > 0; off >>= 1) acc += __shfl_down(acc, off, 64);
    if (lane == 0) wsum[w] = acc;
    __syncthreads();
    if (t == 0) atomicAdd(out, wsum[0] + wsum[1] + wsum[2] + wsum[3]);
}

extern "C" void kernel_launch(void* const* d_in, const int* in_sizes, int n_in,
                              void* d_out, int out_size, void* d_ws, size_t ws_size,
                              hipStream_t stream)
{
    const float* A    = (const float*)d_in[0];   // [N,N]
    const float* beta = (const float*)d_in[1];   // [N]
    const float* a    = (const float*)d_in[2];   // [1]
    const float* Z    = (const float*)d_in[3];   // [K,N]
    const float* C    = (const float*)d_in[4];   // [N,K]
    float* out = (float*)d_out;

    float* ws    = (float*)d_ws;
    float* ZsT   = ws;                      // N*K floats
    float* Upart = ws + (size_t)N * K;      // NPB*64 floats

    hipMemsetAsync(out, 0, sizeof(float), stream);   // harness poisons out each call

    prep_stats<<<NPB, 256, 0, stream>>>(Z, C, A, beta, a, ZsT, Upart, out);

    dim3 grid(N / RB, N / CB);
    pair_ll<<<grid, 256, 0, stream>>>(A, beta, a, ZsT, Upart, out);
}